// Round 2
// baseline (280.575 us; speedup 1.0000x reference)
//
#include <hip/hip_runtime.h>
#include <math.h>

// Problem constants (B=64, P=2, H=512, W=512)
#define HH 512
#define WW 512
#define BP 128                  // B*P pairs
#define PLANE (HH * WW)         // 262144 elems per (b,p) plane
#define SEG2 32                 // segments per pair
#define SEG_FLOATS 8192         // floats per segment (32 KB)
#define NPART2 (BP * SEG2)      // 4096 partial records per quantity

// ws float layout: [0,4096) sum, [4096,8192) sumx, [8192,12288) sumy,
// [12288,16384) maxval ; ints at float offset [16384,20480) maxidx. 80 KiB.

// R6: R4 (named loads) and R5 (asm memory fence) both failed to raise
// VGPR_Count past 32 — the allocator refuses to keep 8 float4 loads live, so
// per-wave MLP stays ~1-2 and the kernel is latency-bound at 2.7 TB/s
// delivered. Fix: take registers out of the path entirely. Stage each
// block's 32 KB segment into LDS via global_load_lds width=16 (DMA path,
// zero data VGPRs, fire-and-forget). 8 instrs/wave all in flight ->
// 32 KB/block outstanding; 5 blocks/CU (LDS kept at exactly 32768 B by
// aliasing reduction scratch into the main buffer) -> up to 160 KB/CU in
// flight vs the ~10 KB Little's law requires at 6.3 TB/s.
__device__ __forceinline__ void gload_lds16(const float* g, float* l)
{
    __builtin_amdgcn_global_load_lds(
        (const __attribute__((address_space(1))) void*)g,
        (__attribute__((address_space(3))) void*)l, 16, 0, 0);
}

__global__ __launch_bounds__(256, 2) void dsnt_partial(
    const float* __restrict__ inp, const float* __restrict__ tgt,
    float* __restrict__ wsf, int* __restrict__ wsi)
{
    const int tid  = threadIdx.x;
    const int blk  = blockIdx.x;
    const int lane = tid & 63, wid = tid >> 6;
    const float inv = 1.0f / 512.0f;

    __shared__ float lds[SEG_FLOATS];   // exactly 32 KB; scratch aliased below

    const bool is_sm = (blk < NPART2);
    const int  b2    = is_sm ? blk : blk - NPART2;
    const int  pair  = b2 >> 5;
    const int  seg   = b2 & 31;
    const float* __restrict__ gbase =
        (is_sm ? inp : tgt) + (size_t)pair * PLANE + seg * SEG_FLOATS;
    const int segbase = seg * SEG_FLOATS;

    // ---- DMA stage: 32 instrs (8/wave), each moves 1 KB (64 lanes x 16 B).
    // LDS dest is wave-uniform (k depends only on wid); global src per-lane.
#pragma unroll
    for (int r = 0; r < 8; ++r) {
        const int k = wid * 8 + r;      // 0..31, uniform within wave
        gload_lds16(gbase + k * 256 + lane * 4, &lds[k * 256]);
    }
    __syncthreads();                    // drains vmcnt, then barrier

    const float4* __restrict__ lp = (const float4*)lds;

    if (is_sm) {
        // ---- softmax partial sums ----
        float s = 0.0f, sx = 0.0f, sy = 0.0f;
#pragma unroll
        for (int j = 0; j < 8; ++j) {
            const float4 v = lp[j * 256 + tid];
            const int f = segbase + (j * 256 + tid) * 4;  // %4==0, no row cross
            const float yw  = (float)((f >> 9) + 1) * inv;
            const float xw0 = (float)((f & 511) + 1) * inv;
            const float e0 = __expf(v.x);
            const float e1 = __expf(v.y);
            const float e2 = __expf(v.z);
            const float e3 = __expf(v.w);
            const float es = e0 + e1 + e2 + e3;
            s  += es;
            sx += es * xw0 + inv * (e1 + 2.0f * e2 + 3.0f * e3);
            sy += es * yw;
        }

#pragma unroll
        for (int off = 32; off > 0; off >>= 1) {
            s  += __shfl_down(s,  off, 64);
            sx += __shfl_down(sx, off, 64);
            sy += __shfl_down(sy, off, 64);
        }
        __syncthreads();                // all lds reads done; safe to alias
        if (lane == 0) { lds[wid] = s; lds[4 + wid] = sx; lds[8 + wid] = sy; }
        __syncthreads();
        if (tid == 0) {
            float fs = lds[0], fsx = lds[4], fsy = lds[8];
#pragma unroll
            for (int k = 1; k < 4; ++k) {
                fs += lds[k]; fsx += lds[4 + k]; fsy += lds[8 + k];
            }
            wsf[blk]              = fs;
            wsf[NPART2 + blk]     = fsx;
            wsf[2 * NPART2 + blk] = fsy;
        }
    } else {
        // ---- argmax partial over target ----
        float mv = -1.0f;
        int   mi = 0;
#pragma unroll
        for (int j = 0; j < 8; ++j) {
            const float4 v = lp[j * 256 + tid];
            const int f = segbase + (j * 256 + tid) * 4;
            if (v.x > mv) { mv = v.x; mi = f; }
            if (v.y > mv) { mv = v.y; mi = f + 1; }
            if (v.z > mv) { mv = v.z; mi = f + 2; }
            if (v.w > mv) { mv = v.w; mi = f + 3; }
        }

#pragma unroll
        for (int off = 32; off > 0; off >>= 1) {
            const float ov = __shfl_down(mv, off, 64);
            const int   oi = __shfl_down(mi, off, 64);
            if (ov > mv || (ov == mv && oi < mi)) { mv = ov; mi = oi; }
        }
        __syncthreads();                // all lds reads done; safe to alias
        int* ldsi = (int*)lds;
        if (lane == 0) { lds[wid] = mv; ldsi[4 + wid] = mi; }
        __syncthreads();
        if (tid == 0) {
            float fmv = lds[0];
            int   fmi = ldsi[4];
#pragma unroll
            for (int k = 1; k < 4; ++k)
                if (lds[k] > fmv || (lds[k] == fmv && ldsi[4 + k] < fmi)) {
                    fmv = lds[k]; fmi = ldsi[4 + k];
                }
            wsf[3 * NPART2 + b2] = fmv;
            wsi[b2]              = fmi;
        }
    }
}

__global__ __launch_bounds__(128) void dsnt_finalize(
    const float* __restrict__ wsf, const int* __restrict__ wsi,
    float* __restrict__ out)
{
    __shared__ float px[BP], py[BP], tx[BP], ty[BP];
    __shared__ float wsum[2];
    const int tid = threadIdx.x; // 0..127, one pair per thread

    {
        float s = 0.0f, sx = 0.0f, sy = 0.0f, mv = -1.0f;
        int mi = 0;
#pragma unroll
        for (int k = 0; k < SEG2; ++k) {
            const int i = tid * SEG2 + k;  // segs in ascending index order
            s  += wsf[i];
            sx += wsf[NPART2 + i];
            sy += wsf[2 * NPART2 + i];
            const float v = wsf[3 * NPART2 + i];
            const int  ii = wsi[i];
            if (v > mv || (v == mv && ii < mi)) { mv = v; mi = ii; }
        }
        px[tid] = sx / s;
        py[tid] = sy / s;
        tx[tid] = (float)((mi & 511) + 1) * (1.0f / 512.0f);
        ty[tid] = (float)((mi >> 9) + 1) * (1.0f / 512.0f);
    }
    __syncthreads();

    float term = 0.0f;
    if (tid < 64) {
        const int b = tid;
        const float px0 = px[2 * b], px1 = px[2 * b + 1];
        const float py0 = py[2 * b], py1 = py[2 * b + 1];
        const float tx0 = tx[2 * b], tx1 = tx[2 * b + 1];
        const float ty0 = ty[2 * b], ty1 = ty[2 * b + 1];

        const float ed0 = sqrtf((tx0 - px0) * (tx0 - px0) + (ty0 - py0) * (ty0 - py0));
        const float ed1 = sqrtf((tx1 - px1) * (tx1 - px1) + (ty1 - py1) * (ty1 - py1));

        const float pvx = px0 - px1, pvy = py0 - py1;
        const float tvx = tx0 - tx1, tvy = ty0 - ty1;
        const float pd = sqrtf(pvx * pvx + pvy * pvy);
        const float td = sqrtf(tvx * tvx + tvy * tvy);
        const float dot = pvx * tvx + pvy * tvy;
        const float cosd = 1.0f - cosf(dot / (pd * td));
        term = ed0 + ed1 + fabsf(pd - td) + cosd;
    }

#pragma unroll
    for (int off = 32; off > 0; off >>= 1)
        term += __shfl_down(term, off, 64);
    const int lane = tid & 63, wid = tid >> 6;
    if (lane == 0) wsum[wid] = term;
    __syncthreads();
    if (tid == 0) out[0] = (wsum[0] + wsum[1]) * (1.0f / 64.0f);
}

extern "C" void kernel_launch(void* const* d_in, const int* in_sizes, int n_in,
                              void* d_out, int out_size, void* d_ws, size_t ws_size,
                              hipStream_t stream)
{
    const float* inp = (const float*)d_in[0];
    const float* tgt = (const float*)d_in[1];
    float* out = (float*)d_out;
    float* wsf = (float*)d_ws;
    int*   wsi = (int*)((float*)d_ws + 4 * NPART2);

    dsnt_partial<<<2 * NPART2, 256, 0, stream>>>(inp, tgt, wsf, wsi);
    dsnt_finalize<<<1, 128, 0, stream>>>(wsf, wsi, out);
}